// Round 2
// 274.171 us; speedup vs baseline: 1.2961x; 1.2961x over previous
//
#include <hip/hip_runtime.h>

// EncodecEuclideanCodebook — R6 (resubmit; R1 bench was an infra failure,
// "container failed twice" with no pytest/counter data — kernel unchanged).
//   x: [131072, 128] fp32, embed: [1024, 128] fp32.
//   out: quantize [131072*128] f32, then embed_ind [131072] (indices as f32).
//
// score = 2*x.e - ||e||^2 (argmax-equivalent). Approx: K=256 fp16 MFMA GEMM
// (x_hi + x_lo) . fp16(e); only dropped term is 2*x.(e - fp16(e)),
// sigma ~ 0.0063 -> MARGIN 0.05 = 8 sigma. Flagged rows (est ~1%) re-scored
// exactly in fp32. Gather fused into vq/refine epilogues.
//
// R5 lesson (counters): bh/bl[4][4]+acc[4][4] = 192+ live VGPRs vs 128
// allocated (waves_per_eu attr did NOT raise the budget) -> guaranteed spill;
// WRITE_SIZE 131MB vs 68MB of real stores = 63MB scratch writes; MfmaUtil 14%.
// R6 fix: fit 128 regs BY DESIGN instead of fighting the allocator:
//   64 rows/block, wave tile 32 rows x 64 bins: bh[4][2] cached (32 regs),
//   acc[4][2] (32 regs), bl STREAMED from LDS per stage (xl_s stays live).
//   Peak ~115 VGPR, LDS 48KB -> 2 blocks/CU. prep/refine/numerics unchanged.

#define N_ROWS (64 * 2048)
#define DIM 128
#define BINS 1024
#define MARGIN 0.05f

typedef __attribute__((ext_vector_type(8))) _Float16 half8;  // 16 B = 4 VGPR
typedef __attribute__((ext_vector_type(4))) float f32x4;

__device__ __forceinline__ void glds16(const void* g, void* l) {
    __builtin_amdgcn_global_load_lds((const __attribute__((address_space(1))) char*)g,
                                     (__attribute__((address_space(3))) char*)l, 16, 0, 0);
}

// e_img: 16 stages x 16 KB fp16. Stage S = chunk*4 + ks holds bins
// [256*chunk,+256) x k [32*ks,+32); byte off = b*64 + 16*(g2 ^ ((b>>2)&3)).
__global__ __launch_bounds__(256) void prep_kernel(const float* __restrict__ embed,
                                                   _Float16* __restrict__ e_img,
                                                   float* __restrict__ esq_g,
                                                   int* __restrict__ counter) {
    int bin = blockIdx.x * 256 + threadIdx.x;
    if (bin == 0) *counter = 0;
    const float4* e4 = (const float4*)(embed + (size_t)bin * DIM);
    int c = bin >> 8, b = bin & 255;
    float s = 0.f;
#pragma unroll
    for (int g = 0; g < 16; ++g) {
        float4 v0 = e4[2 * g], v1 = e4[2 * g + 1];
        s += v0.x * v0.x + v0.y * v0.y + v0.z * v0.z + v0.w * v0.w;
        s += v1.x * v1.x + v1.y * v1.y + v1.z * v1.z + v1.w * v1.w;
        float f[8] = {v0.x, v0.y, v0.z, v0.w, v1.x, v1.y, v1.z, v1.w};
        half8 H;
#pragma unroll
        for (int j = 0; j < 8; ++j) H[j] = (_Float16)f[j];
        int ks = g >> 2, g2 = g & 3;
        size_t off = ((size_t)(c * 4 + ks) << 14) + (size_t)b * 64 + 16 * (g2 ^ ((b >> 2) & 3));
        *(half8*)((char*)e_img + off) = H;
    }
    esq_g[bin] = s;
}

// 512 threads = 8 waves. Wave wv: row-half h = wv>>2 (32 rows), bin-quarter
// bq = wv&3 (64 bins of each 256-bin chunk). Wave tile 64 bins x 32 rows.
// LDS: [0,16K) x_hi (dead after bh preload -> even e-stage buf),
//      [16K,32K) x_lo (LIVE: bl streamed from it every stage),
//      [32K,48K) odd e-stage buf.
__global__ __launch_bounds__(512) void vq_mfma_kernel(const float* __restrict__ x,
                                                      const _Float16* __restrict__ e_img,
                                                      const float* __restrict__ esq_g,
                                                      const float* __restrict__ embed,
                                                      float* __restrict__ out_idx,
                                                      float* __restrict__ out_q,
                                                      int* __restrict__ list,
                                                      int* __restrict__ counter) {
    __shared__ __align__(16) char smem[49152];
    char* xl_s = smem + 16384;

    const int t = threadIdx.x;
    const int wv = t >> 6, lane = t & 63, q = lane >> 4, L15 = lane & 15;
    const int h = wv >> 2, bq = wv & 3;
    const int R0 = blockIdx.x * 64;

    // ---- convert x tile (64 rows) -> fp16 hi/lo in LDS (group g at g^(row&7)) ----
    {
        const float4* xg = (const float4*)(x + (size_t)R0 * DIM);
#pragma unroll
        for (int qq = 0; qq < 2; ++qq) {
            int G = qq * 512 + t;
            int row = G >> 4, g = G & 15;
            float4 v0 = xg[row * 32 + 2 * g];
            float4 v1 = xg[row * 32 + 2 * g + 1];
            float f[8] = {v0.x, v0.y, v0.z, v0.w, v1.x, v1.y, v1.z, v1.w};
            half8 H, L;
#pragma unroll
            for (int j = 0; j < 8; ++j) {
                _Float16 hv = (_Float16)f[j];
                H[j] = hv;
                L[j] = (_Float16)(f[j] - (float)hv);
            }
            int off = row * 256 + 16 * (g ^ (row & 7));
            *(half8*)(smem + off) = H;
            *(half8*)(xl_s + off) = L;
        }
    }
    __syncthreads();

    // ---- preload x_hi B-fragments only: rows 32h+16nt+L15, k-group (ks<<2)|q ----
    half8 bh[4][2];
    const int rbase = (32 * h + L15) * 256;
#pragma unroll
    for (int ks = 0; ks < 4; ++ks) {
        const int sB = 16 * ((((ks << 2) | q)) ^ (L15 & 7));
#pragma unroll
        for (int nt = 0; nt < 2; ++nt)
            bh[ks][nt] = *(const half8*)(smem + rbase + nt * 4096 + sB);
    }
    __syncthreads();   // x_hi region dead -> even e-stage buffer

    const int aOff = (64 * bq + L15) * 64 + 16 * (q ^ ((L15 >> 2) & 3));

    // prefetch stage 0 (16 KB, 2 KB per wave: 2 wave-uniform 1KB segments)
    {
        const char* src = (const char*)e_img;
#pragma unroll
        for (int i = 0; i < 2; ++i) {
            int off = ((i << 3) | wv) << 10;
            glds16(src + off + lane * 16, smem + off);
        }
    }

    float best[2], sec[2];
    int bidx[2];
#pragma unroll
    for (int nt = 0; nt < 2; ++nt) { best[nt] = -3.4e38f; sec[nt] = -3.4e38f; bidx[nt] = 0; }

    for (int c = 0; c < 4; ++c) {                 // 4 chunks of 256 bins
        f32x4 acc[4][2];
#pragma unroll
        for (int mt = 0; mt < 4; ++mt)
#pragma unroll
            for (int nt = 0; nt < 2; ++nt) acc[mt][nt] = (f32x4){0.f, 0.f, 0.f, 0.f};

#pragma unroll
        for (int s = 0; s < 4; ++s) {             // 4 k-stages of 32
            const int gs = c * 4 + s;
            __syncthreads();                      // stage gs landed; prev readers done
            if (gs < 15) {
                const char* src = (const char*)e_img + ((size_t)(gs + 1) << 14);
                char* dst = smem + ((gs + 1) & 1) * 32768;
#pragma unroll
                for (int i = 0; i < 2; ++i) {
                    int off = ((i << 3) | wv) << 10;
                    glds16(src + off + lane * 16, dst + off);
                }
            }
            const char* buf = smem + (gs & 1) * 32768;
            half8 a[4];
#pragma unroll
            for (int mt = 0; mt < 4; ++mt)
                a[mt] = *(const half8*)(buf + aOff + mt * 1024);
            half8 bl[2];
            const int sB = 16 * ((((s << 2) | q)) ^ (L15 & 7));
#pragma unroll
            for (int nt = 0; nt < 2; ++nt)
                bl[nt] = *(const half8*)(xl_s + rbase + nt * 4096 + sB);
#pragma unroll
            for (int mt = 0; mt < 4; ++mt)
#pragma unroll
                for (int nt = 0; nt < 2; ++nt) {
                    acc[mt][nt] = __builtin_amdgcn_mfma_f32_16x16x32_f16(a[mt], bh[s][nt], acc[mt][nt], 0, 0, 0);
                    acc[mt][nt] = __builtin_amdgcn_mfma_f32_16x16x32_f16(a[mt], bl[nt], acc[mt][nt], 0, 0, 0);
                }
        }

        // ---- chunk epilogue: per-lane top-2 over its 16 bins (ascending) ----
        const float* ep = esq_g + 256 * c + 64 * bq + 4 * q;
#pragma unroll
        for (int mt = 0; mt < 4; ++mt)
#pragma unroll
            for (int r = 0; r < 4; ++r) {
                int bin = 256 * c + 64 * bq + 16 * mt + 4 * q + r;
                float e2 = ep[16 * mt + r];
#pragma unroll
                for (int nt = 0; nt < 2; ++nt) {
                    float sc = 2.f * acc[mt][nt][r] - e2;
                    if (sc > best[nt]) { sec[nt] = best[nt]; best[nt] = sc; bidx[nt] = bin; }
                    else if (sc > sec[nt]) sec[nt] = sc;
                }
            }
    }

    // ---- cross-quad top-2 merge (within wave) ----
#pragma unroll
    for (int nt = 0; nt < 2; ++nt) {
        for (int off = 16; off <= 32; off <<= 1) {
            float ob = __shfl_xor(best[nt], off);
            float os = __shfl_xor(sec[nt], off);
            int oi = __shfl_xor(bidx[nt], off);
            if (ob > best[nt]) { sec[nt] = fmaxf(best[nt], os); best[nt] = ob; bidx[nt] = oi; }
            else sec[nt] = fmaxf(sec[nt], ob);
        }
    }
    __syncthreads();                              // e-bufs + x_lo dead -> scratch
    float* sv = (float*)smem;                     // [8 waves][32 rows][b,s,i]
    int* fidx = (int*)(smem + 4096);              // [64]
    if (q == 0) {
#pragma unroll
        for (int nt = 0; nt < 2; ++nt) {
            int base = (wv * 32 + 16 * nt + L15) * 3;
            sv[base] = best[nt]; sv[base + 1] = sec[nt];
            ((int*)sv)[base + 2] = bidx[nt];
        }
    }
    __syncthreads();
    if (t < 64) {
        int hh = t >> 5, r32 = t & 31;
        int base0 = ((4 * hh) * 32 + r32) * 3;
        float b0 = sv[base0], s0 = sv[base0 + 1];
        int i0 = ((int*)sv)[base0 + 2];
        for (int w = 1; w < 4; ++w) {
            int base = ((4 * hh + w) * 32 + r32) * 3;
            float ob = sv[base], os = sv[base + 1];
            int oi = ((int*)sv)[base + 2];
            if (ob > b0) { s0 = fmaxf(b0, os); b0 = ob; i0 = oi; }
            else s0 = fmaxf(s0, ob);
        }
        out_idx[R0 + t] = (float)i0;
        fidx[t] = i0;
        if (b0 - s0 < MARGIN) {
            int pos = atomicAdd(counter, 1);
            list[pos] = R0 + t;
        }
    }
    __syncthreads();

    // ---- fused gather: 64 rows x 32 float4 = 4 per thread ----
    {
        const float4* eg = (const float4*)embed;
        float4* og = (float4*)(out_q + (size_t)R0 * DIM);
#pragma unroll
        for (int i = 0; i < 4; ++i) {
            int f = i * 512 + t;
            int r = f >> 5, cc = f & 31;
            og[(size_t)r * 32 + cc] = eg[(size_t)fidx[r] * 32 + cc];
        }
    }
}

// Compacted exact fp32 refine (16 flagged rows x 1024 bins per tile), with
// fused gather for its rows. First-max tie-break = reference semantics.
#define SWB(r, c4) ((r) * 128 + 4 * ((c4) ^ ((r) & 31)))
__global__ __launch_bounds__(256) void refine_kernel(const float* __restrict__ x,
                                                     const float* __restrict__ embed,
                                                     const float* __restrict__ esq_g,
                                                     float* __restrict__ out_idx,
                                                     float* __restrict__ out_q,
                                                     const int* __restrict__ list,
                                                     const int* __restrict__ counter) {
    __shared__ float xr[16 * 128];    // 8 KB
    __shared__ float bs[64 * 128];    // 32 KB
    __shared__ int rowbuf[16];
    __shared__ int ridx[16];

    const int t = threadIdx.x;
    const int tx = t & 63;
    const int ty = t >> 6;
    const int F = *counter;

    for (int tile = blockIdx.x; tile * 16 < F; tile += gridDim.x) {
        const int base = tile * 16;
        __syncthreads();
        if (t < 16) rowbuf[t] = list[min(base + t, F - 1)];
        __syncthreads();
#pragma unroll
        for (int i = 0; i < 2; ++i) {
            int f = i * 256 + t;
            int r = f >> 5, cc = f & 31;
            float4 v = ((const float4*)(x + (size_t)rowbuf[r] * DIM))[cc];
            *(float4*)&xr[r * 128 + cc * 4] = v;
        }

        float bb[4]; int bi[4];
#pragma unroll
        for (int rr = 0; rr < 4; ++rr) { bb[rr] = -3.4e38f; bi[rr] = 0; }

        for (int chunk = 0; chunk < 16; ++chunk) {
            __syncthreads();
            const float4* eg = (const float4*)(embed + (size_t)chunk * 64 * DIM);
#pragma unroll
            for (int i = 0; i < 8; ++i) {
                int f = i * 256 + t;
                int r = f >> 5, cc = f & 31;
                float4 v = eg[f];
                *(float4*)&bs[SWB(r, cc)] = v;
            }
            __syncthreads();

            float acc[4];
#pragma unroll
            for (int rr = 0; rr < 4; ++rr) acc[rr] = 0.f;
#pragma unroll 8
            for (int k4 = 0; k4 < 32; ++k4) {
                float4 b = *(const float4*)&bs[SWB(tx, k4)];
#pragma unroll
                for (int rr = 0; rr < 4; ++rr) {
                    float4 a = *(const float4*)&xr[(4 * ty + rr) * 128 + k4 * 4];
                    acc[rr] = fmaf(a.x, b.x, acc[rr]);
                    acc[rr] = fmaf(a.y, b.y, acc[rr]);
                    acc[rr] = fmaf(a.z, b.z, acc[rr]);
                    acc[rr] = fmaf(a.w, b.w, acc[rr]);
                }
            }
            const int bin = chunk * 64 + tx;
            const float e2 = esq_g[bin];
#pragma unroll
            for (int rr = 0; rr < 4; ++rr) {
                float sc = 2.f * acc[rr] - e2;
                if (sc > bb[rr]) { bb[rr] = sc; bi[rr] = bin; }
            }
        }

        __syncthreads();
        float* vals = bs;
        int* idxs = (int*)(bs + 1024);
#pragma unroll
        for (int rr = 0; rr < 4; ++rr) {
            vals[(4 * ty + rr) * 64 + tx] = bb[rr];
            idxs[(4 * ty + rr) * 64 + tx] = bi[rr];
        }
        __syncthreads();
        if (t < 16) {
            float bv = vals[t * 64];
            int bix = idxs[t * 64];
            for (int j = 1; j < 64; ++j) {
                float v = vals[t * 64 + j];
                int id = idxs[t * 64 + j];
                if (v > bv || (v == bv && id < bix)) { bv = v; bix = id; }
            }
            ridx[t] = bix;
            if (base + t < F) out_idx[rowbuf[t]] = (float)bix;
        }
        __syncthreads();
        // fused gather for this tile's rows (dup tail rows rewrite same data)
        {
            const float4* eg = (const float4*)embed;
#pragma unroll
            for (int i = 0; i < 2; ++i) {
                int f = i * 256 + t;
                int r = f >> 5, cc = f & 31;
                float4* og = (float4*)(out_q + (size_t)rowbuf[r] * DIM);
                og[cc] = eg[(size_t)ridx[r] * 32 + cc];
            }
        }
    }
}

extern "C" void kernel_launch(void* const* d_in, const int* in_sizes, int n_in,
                              void* d_out, int out_size, void* d_ws, size_t ws_size,
                              hipStream_t stream) {
    const float* x = (const float*)d_in[0];
    const float* embed = (const float*)d_in[1];
    float* out_q = (float*)d_out;
    float* out_idx = out_q + (size_t)N_ROWS * DIM;
    char* wsb = (char*)d_ws;
    _Float16* e_img = (_Float16*)wsb;                         // 256 KB (16 x 16 KB)
    float* esq_g = (float*)(wsb + (16 << 14));                // 4 KB
    int* counter = (int*)(wsb + (16 << 14) + 4096);           // 4 B (+pad)
    int* list = (int*)(wsb + (16 << 14) + 4096 + 128);        // 512 KB

    prep_kernel<<<BINS / 256, 256, 0, stream>>>(embed, e_img, esq_g, counter);
    vq_mfma_kernel<<<N_ROWS / 64, 512, 0, stream>>>(x, e_img, esq_g, embed,
                                                    out_idx, out_q, list, counter);
    refine_kernel<<<1024, 256, 0, stream>>>(x, embed, esq_g, out_idx, out_q, list, counter);
}

// Round 3
// 255.461 us; speedup vs baseline: 1.3911x; 1.0732x over previous
//
#include <hip/hip_runtime.h>

// EncodecEuclideanCodebook — R7.
//   x: [131072, 128] fp32, embed: [1024, 128] fp32.
//   out: quantize [131072*128] f32, then embed_ind [131072] (indices as f32).
//
// score = 2*x.e - ||e||^2 (argmax-equivalent). Approx: K=128 fp16 MFMA GEMM
// fp16(x) . fp16(e). err = 2(x.de + xl.e) sigma ~ 4.5e-3 -> MARGIN 0.10 = 22
// sigma. Flagged rows (~1%) re-scored exactly in fp32 by refine_kernel.
// Gather fused into vq/refine epilogues.
//
// R6 post-mortem: spill fixed (VGPR 64, WRITE 66MB = real stores), vq 202->118.
// But MfmaUtil 24 / VALU 52 / HBM 11% / conflicts at 2-way floor => latency-
// bound: 16 barrier-drained stages of ~150cyc compute at 41% occupancy
// (48KB LDS ~ 2 blocks/CU). Non-vq time constant 155-156us across R5/R6
// (prep+refine kept byte-identical to keep tracking it).
// R7: drop x_lo GEMM (halves MFMA + LDS reads), MARGIN 0.05->0.10 (err budget
// 22 sigma, flag ~1%, refine still 1-tile-deep), LDS 48->36KB => 4 blocks/CU
// (full 32-wave occupancy at VGPR<=64), esq staged in LDS for the epilogue.

#define N_ROWS (64 * 2048)
#define DIM 128
#define BINS 1024
#define MARGIN 0.10f

typedef __attribute__((ext_vector_type(8))) _Float16 half8;  // 16 B = 4 VGPR
typedef __attribute__((ext_vector_type(4))) float f32x4;

__device__ __forceinline__ void glds16(const void* g, void* l) {
    __builtin_amdgcn_global_load_lds((const __attribute__((address_space(1))) char*)g,
                                     (__attribute__((address_space(3))) char*)l, 16, 0, 0);
}

// e_img: 16 stages x 16 KB fp16. Stage S = chunk*4 + ks holds bins
// [256*chunk,+256) x k [32*ks,+32); byte off = b*64 + 16*(g2 ^ ((b>>2)&3)).
__global__ __launch_bounds__(256) void prep_kernel(const float* __restrict__ embed,
                                                   _Float16* __restrict__ e_img,
                                                   float* __restrict__ esq_g,
                                                   int* __restrict__ counter) {
    int bin = blockIdx.x * 256 + threadIdx.x;
    if (bin == 0) *counter = 0;
    const float4* e4 = (const float4*)(embed + (size_t)bin * DIM);
    int c = bin >> 8, b = bin & 255;
    float s = 0.f;
#pragma unroll
    for (int g = 0; g < 16; ++g) {
        float4 v0 = e4[2 * g], v1 = e4[2 * g + 1];
        s += v0.x * v0.x + v0.y * v0.y + v0.z * v0.z + v0.w * v0.w;
        s += v1.x * v1.x + v1.y * v1.y + v1.z * v1.z + v1.w * v1.w;
        float f[8] = {v0.x, v0.y, v0.z, v0.w, v1.x, v1.y, v1.z, v1.w};
        half8 H;
#pragma unroll
        for (int j = 0; j < 8; ++j) H[j] = (_Float16)f[j];
        int ks = g >> 2, g2 = g & 3;
        size_t off = ((size_t)(c * 4 + ks) << 14) + (size_t)b * 64 + 16 * (g2 ^ ((b >> 2) & 3));
        *(half8*)((char*)e_img + off) = H;
    }
    esq_g[bin] = s;
}

// 512 threads = 8 waves. Wave wv: row-half h = wv>>2 (32 rows), bin-quarter
// bq = wv&3 (64 bins of each 256-bin chunk). Wave tile 64 bins x 32 rows.
// LDS 36 KB: [0,16K) xh (dead after bh preload -> even e-stage buf),
//            [16K,32K) odd e-stage buf, [32K,36K) esq (live whole kernel).
__global__ __launch_bounds__(512) void vq_mfma_kernel(const float* __restrict__ x,
                                                      const _Float16* __restrict__ e_img,
                                                      const float* __restrict__ esq_g,
                                                      const float* __restrict__ embed,
                                                      float* __restrict__ out_idx,
                                                      float* __restrict__ out_q,
                                                      int* __restrict__ list,
                                                      int* __restrict__ counter) {
    __shared__ __align__(16) char smem[36864];
    float* esq_s = (float*)(smem + 32768);

    const int t = threadIdx.x;
    const int wv = t >> 6, lane = t & 63, q = lane >> 4, L15 = lane & 15;
    const int h = wv >> 2, bq = wv & 3;
    const int R0 = blockIdx.x * 64;

    // ---- stage esq -> LDS; convert x tile (64 rows) -> fp16 in LDS ----
    {
        esq_s[t] = esq_g[t];
        esq_s[t + 512] = esq_g[t + 512];
        const float4* xg = (const float4*)(x + (size_t)R0 * DIM);
#pragma unroll
        for (int qq = 0; qq < 2; ++qq) {
            int G = qq * 512 + t;
            int row = G >> 4, g = G & 15;
            float4 v0 = xg[row * 32 + 2 * g];
            float4 v1 = xg[row * 32 + 2 * g + 1];
            float f[8] = {v0.x, v0.y, v0.z, v0.w, v1.x, v1.y, v1.z, v1.w};
            half8 H;
#pragma unroll
            for (int j = 0; j < 8; ++j) H[j] = (_Float16)f[j];
            int off = row * 256 + 16 * (g ^ (row & 7));
            *(half8*)(smem + off) = H;
        }
    }
    __syncthreads();

    // ---- preload x B-fragments: rows 32h+16nt+L15, k-group (ks<<2)|q ----
    half8 bh[4][2];
    const int rbase = (32 * h + L15) * 256;
#pragma unroll
    for (int ks = 0; ks < 4; ++ks) {
        const int sB = 16 * ((((ks << 2) | q)) ^ (L15 & 7));
#pragma unroll
        for (int nt = 0; nt < 2; ++nt)
            bh[ks][nt] = *(const half8*)(smem + rbase + nt * 4096 + sB);
    }
    __syncthreads();   // xh region dead -> even e-stage buffer

    const int aOff = (64 * bq + L15) * 64 + 16 * (q ^ ((L15 >> 2) & 3));

    // prefetch stage 0 (16 KB, 2 KB per wave: 2 wave-uniform 1KB segments)
    {
        const char* src = (const char*)e_img;
#pragma unroll
        for (int i = 0; i < 2; ++i) {
            int off = ((i << 3) | wv) << 10;
            glds16(src + off + lane * 16, smem + off);
        }
    }

    float best[2], sec[2];
    int bidx[2];
#pragma unroll
    for (int nt = 0; nt < 2; ++nt) { best[nt] = -3.4e38f; sec[nt] = -3.4e38f; bidx[nt] = 0; }

    for (int c = 0; c < 4; ++c) {                 // 4 chunks of 256 bins
        f32x4 acc[4][2];
#pragma unroll
        for (int mt = 0; mt < 4; ++mt)
#pragma unroll
            for (int nt = 0; nt < 2; ++nt) acc[mt][nt] = (f32x4){0.f, 0.f, 0.f, 0.f};

#pragma unroll
        for (int s = 0; s < 4; ++s) {             // 4 k-stages of 32
            const int gs = c * 4 + s;
            __syncthreads();                      // stage gs landed; prev readers done
            if (gs < 15) {
                const char* src = (const char*)e_img + ((size_t)(gs + 1) << 14);
                char* dst = smem + ((gs + 1) & 1) * 16384;
#pragma unroll
                for (int i = 0; i < 2; ++i) {
                    int off = ((i << 3) | wv) << 10;
                    glds16(src + off + lane * 16, dst + off);
                }
            }
            const char* buf = smem + (gs & 1) * 16384;
            half8 a[4];
#pragma unroll
            for (int mt = 0; mt < 4; ++mt)
                a[mt] = *(const half8*)(buf + aOff + mt * 1024);
#pragma unroll
            for (int mt = 0; mt < 4; ++mt)
#pragma unroll
                for (int nt = 0; nt < 2; ++nt)
                    acc[mt][nt] = __builtin_amdgcn_mfma_f32_16x16x32_f16(a[mt], bh[s][nt], acc[mt][nt], 0, 0, 0);
        }

        // ---- chunk epilogue: per-lane top-2 over its 16 bins (ascending) ----
#pragma unroll
        for (int mt = 0; mt < 4; ++mt)
#pragma unroll
            for (int r = 0; r < 4; ++r) {
                int bin = 256 * c + 64 * bq + 16 * mt + 4 * q + r;
                float e2 = esq_s[bin];
#pragma unroll
                for (int nt = 0; nt < 2; ++nt) {
                    float sc = 2.f * acc[mt][nt][r] - e2;
                    if (sc > best[nt]) { sec[nt] = best[nt]; best[nt] = sc; bidx[nt] = bin; }
                    else if (sc > sec[nt]) sec[nt] = sc;
                }
            }
    }

    // ---- cross-quad top-2 merge (within wave) ----
#pragma unroll
    for (int nt = 0; nt < 2; ++nt) {
        for (int off = 16; off <= 32; off <<= 1) {
            float ob = __shfl_xor(best[nt], off);
            float os = __shfl_xor(sec[nt], off);
            int oi = __shfl_xor(bidx[nt], off);
            if (ob > best[nt]) { sec[nt] = fmaxf(best[nt], os); best[nt] = ob; bidx[nt] = oi; }
            else sec[nt] = fmaxf(sec[nt], ob);
        }
    }
    __syncthreads();                              // e-bufs dead -> scratch
    float* sv = (float*)smem;                     // [8 waves][32 rows][b,s,i]
    int* fidx = (int*)(smem + 4096);              // [64]
    if (q == 0) {
#pragma unroll
        for (int nt = 0; nt < 2; ++nt) {
            int base = (wv * 32 + 16 * nt + L15) * 3;
            sv[base] = best[nt]; sv[base + 1] = sec[nt];
            ((int*)sv)[base + 2] = bidx[nt];
        }
    }
    __syncthreads();
    if (t < 64) {
        int hh = t >> 5, r32 = t & 31;
        int base0 = ((4 * hh) * 32 + r32) * 3;
        float b0 = sv[base0], s0 = sv[base0 + 1];
        int i0 = ((int*)sv)[base0 + 2];
        for (int w = 1; w < 4; ++w) {
            int base = ((4 * hh + w) * 32 + r32) * 3;
            float ob = sv[base], os = sv[base + 1];
            int oi = ((int*)sv)[base + 2];
            if (ob > b0) { s0 = fmaxf(b0, os); b0 = ob; i0 = oi; }
            else s0 = fmaxf(s0, ob);
        }
        out_idx[R0 + t] = (float)i0;
        fidx[t] = i0;
        if (b0 - s0 < MARGIN) {
            int pos = atomicAdd(counter, 1);
            list[pos] = R0 + t;
        }
    }
    __syncthreads();

    // ---- fused gather: 64 rows x 32 float4 = 4 per thread ----
    {
        const float4* eg = (const float4*)embed;
        float4* og = (float4*)(out_q + (size_t)R0 * DIM);
#pragma unroll
        for (int i = 0; i < 4; ++i) {
            int f = i * 512 + t;
            int r = f >> 5, cc = f & 31;
            og[(size_t)r * 32 + cc] = eg[(size_t)fidx[r] * 32 + cc];
        }
    }
}

// Compacted exact fp32 refine (16 flagged rows x 1024 bins per tile), with
// fused gather for its rows. First-max tie-break = reference semantics.
#define SWB(r, c4) ((r) * 128 + 4 * ((c4) ^ ((r) & 31)))
__global__ __launch_bounds__(256) void refine_kernel(const float* __restrict__ x,
                                                     const float* __restrict__ embed,
                                                     const float* __restrict__ esq_g,
                                                     float* __restrict__ out_idx,
                                                     float* __restrict__ out_q,
                                                     const int* __restrict__ list,
                                                     const int* __restrict__ counter) {
    __shared__ float xr[16 * 128];    // 8 KB
    __shared__ float bs[64 * 128];    // 32 KB
    __shared__ int rowbuf[16];
    __shared__ int ridx[16];

    const int t = threadIdx.x;
    const int tx = t & 63;
    const int ty = t >> 6;
    const int F = *counter;

    for (int tile = blockIdx.x; tile * 16 < F; tile += gridDim.x) {
        const int base = tile * 16;
        __syncthreads();
        if (t < 16) rowbuf[t] = list[min(base + t, F - 1)];
        __syncthreads();
#pragma unroll
        for (int i = 0; i < 2; ++i) {
            int f = i * 256 + t;
            int r = f >> 5, cc = f & 31;
            float4 v = ((const float4*)(x + (size_t)rowbuf[r] * DIM))[cc];
            *(float4*)&xr[r * 128 + cc * 4] = v;
        }

        float bb[4]; int bi[4];
#pragma unroll
        for (int rr = 0; rr < 4; ++rr) { bb[rr] = -3.4e38f; bi[rr] = 0; }

        for (int chunk = 0; chunk < 16; ++chunk) {
            __syncthreads();
            const float4* eg = (const float4*)(embed + (size_t)chunk * 64 * DIM);
#pragma unroll
            for (int i = 0; i < 8; ++i) {
                int f = i * 256 + t;
                int r = f >> 5, cc = f & 31;
                float4 v = eg[f];
                *(float4*)&bs[SWB(r, cc)] = v;
            }
            __syncthreads();

            float acc[4];
#pragma unroll
            for (int rr = 0; rr < 4; ++rr) acc[rr] = 0.f;
#pragma unroll 8
            for (int k4 = 0; k4 < 32; ++k4) {
                float4 b = *(const float4*)&bs[SWB(tx, k4)];
#pragma unroll
                for (int rr = 0; rr < 4; ++rr) {
                    float4 a = *(const float4*)&xr[(4 * ty + rr) * 128 + k4 * 4];
                    acc[rr] = fmaf(a.x, b.x, acc[rr]);
                    acc[rr] = fmaf(a.y, b.y, acc[rr]);
                    acc[rr] = fmaf(a.z, b.z, acc[rr]);
                    acc[rr] = fmaf(a.w, b.w, acc[rr]);
                }
            }
            const int bin = chunk * 64 + tx;
            const float e2 = esq_g[bin];
#pragma unroll
            for (int rr = 0; rr < 4; ++rr) {
                float sc = 2.f * acc[rr] - e2;
                if (sc > bb[rr]) { bb[rr] = sc; bi[rr] = bin; }
            }
        }

        __syncthreads();
        float* vals = bs;
        int* idxs = (int*)(bs + 1024);
#pragma unroll
        for (int rr = 0; rr < 4; ++rr) {
            vals[(4 * ty + rr) * 64 + tx] = bb[rr];
            idxs[(4 * ty + rr) * 64 + tx] = bi[rr];
        }
        __syncthreads();
        if (t < 16) {
            float bv = vals[t * 64];
            int bix = idxs[t * 64];
            for (int j = 1; j < 64; ++j) {
                float v = vals[t * 64 + j];
                int id = idxs[t * 64 + j];
                if (v > bv || (v == bv && id < bix)) { bv = v; bix = id; }
            }
            ridx[t] = bix;
            if (base + t < F) out_idx[rowbuf[t]] = (float)bix;
        }
        __syncthreads();
        // fused gather for this tile's rows (dup tail rows rewrite same data)
        {
            const float4* eg = (const float4*)embed;
#pragma unroll
            for (int i = 0; i < 2; ++i) {
                int f = i * 256 + t;
                int r = f >> 5, cc = f & 31;
                float4* og = (float4*)(out_q + (size_t)rowbuf[r] * DIM);
                og[cc] = eg[(size_t)ridx[r] * 32 + cc];
            }
        }
    }
}

extern "C" void kernel_launch(void* const* d_in, const int* in_sizes, int n_in,
                              void* d_out, int out_size, void* d_ws, size_t ws_size,
                              hipStream_t stream) {
    const float* x = (const float*)d_in[0];
    const float* embed = (const float*)d_in[1];
    float* out_q = (float*)d_out;
    float* out_idx = out_q + (size_t)N_ROWS * DIM;
    char* wsb = (char*)d_ws;
    _Float16* e_img = (_Float16*)wsb;                         // 256 KB (16 x 16 KB)
    float* esq_g = (float*)(wsb + (16 << 14));                // 4 KB
    int* counter = (int*)(wsb + (16 << 14) + 4096);           // 4 B (+pad)
    int* list = (int*)(wsb + (16 << 14) + 4096 + 128);        // 512 KB

    prep_kernel<<<BINS / 256, 256, 0, stream>>>(embed, e_img, esq_g, counter);
    vq_mfma_kernel<<<N_ROWS / 64, 512, 0, stream>>>(x, e_img, esq_g, embed,
                                                    out_idx, out_q, list, counter);
    refine_kernel<<<1024, 256, 0, stream>>>(x, embed, esq_g, out_idx, out_q, list, counter);
}

// Round 5
// 247.378 us; speedup vs baseline: 1.4365x; 1.0327x over previous
//
#include <hip/hip_runtime.h>

// EncodecEuclideanCodebook — R8b (R8 + compiler fences after raw s_barrier;
// R4's bench was an infra failure with no pytest/counter data).
//   x: [131072, 128] fp32, embed: [1024, 128] fp32.
//   out: quantize [131072*128] f32, then embed_ind [131072] (indices as f32).
//
// score = 2*x.e - ||e||^2 (argmax-equivalent). Approx: K=128 fp16 MFMA GEMM
// fp16(x) . fp16(e), MARGIN 0.10 (~22 sigma). Flagged rows (~1%) re-scored
// exactly in fp32 by refine_kernel. Gather fused into vq/refine epilogues.
//
// R7 post-mortem: halved MFMA -> vq got SLOWER (118->130us, MfmaUtil 10%).
// Conclusive: bound by the 16 barrier-drained E-stage loads (__syncthreads =
// s_waitcnt vmcnt(0) lgkmcnt(0) before s_barrier), 1-stage lookahead, ~100cyc
// compute vs 200-900cyc load latency. R8 (T3/T4 counted-vmcnt pipeline):
//   raw s_barrier + s_waitcnt vmcnt(2) (never 0 in loop), depth-2 prefetch,
//   3 rotating 16KB e-buffers. Buffer (s+2)%3 == (s-1)%3: its readers finished
//   ds_reads before the stage-s entry barrier (MFMA reg-dep forces lgkmcnt),
//   and the write is issued after that barrier -> race-free; uniform barrier
//   counts -> no deadlock. LDS 52KB -> 3 blocks/CU.
// R8b fix: __builtin_amdgcn_s_barrier() is NOT a compiler fence — a ds_read
// could be hoisted above it (past the point where other waves' glds16 are
// known landed). asm volatile "" memory after each raw barrier pins order.

#define N_ROWS (64 * 2048)
#define DIM 128
#define BINS 1024
#define MARGIN 0.10f

typedef __attribute__((ext_vector_type(8))) _Float16 half8;  // 16 B = 4 VGPR
typedef __attribute__((ext_vector_type(4))) float f32x4;

__device__ __forceinline__ void glds16(const void* g, void* l) {
    __builtin_amdgcn_global_load_lds((const __attribute__((address_space(1))) char*)g,
                                     (__attribute__((address_space(3))) char*)l, 16, 0, 0);
}

// e_img: 16 stages x 16 KB fp16. Stage S = chunk*4 + ks holds bins
// [256*chunk,+256) x k [32*ks,+32); byte off = b*64 + 16*(g2 ^ ((b>>2)&3)).
__global__ __launch_bounds__(256) void prep_kernel(const float* __restrict__ embed,
                                                   _Float16* __restrict__ e_img,
                                                   float* __restrict__ esq_g,
                                                   int* __restrict__ counter) {
    int bin = blockIdx.x * 256 + threadIdx.x;
    if (bin == 0) *counter = 0;
    const float4* e4 = (const float4*)(embed + (size_t)bin * DIM);
    int c = bin >> 8, b = bin & 255;
    float s = 0.f;
#pragma unroll
    for (int g = 0; g < 16; ++g) {
        float4 v0 = e4[2 * g], v1 = e4[2 * g + 1];
        s += v0.x * v0.x + v0.y * v0.y + v0.z * v0.z + v0.w * v0.w;
        s += v1.x * v1.x + v1.y * v1.y + v1.z * v1.z + v1.w * v1.w;
        float f[8] = {v0.x, v0.y, v0.z, v0.w, v1.x, v1.y, v1.z, v1.w};
        half8 H;
#pragma unroll
        for (int j = 0; j < 8; ++j) H[j] = (_Float16)f[j];
        int ks = g >> 2, g2 = g & 3;
        size_t off = ((size_t)(c * 4 + ks) << 14) + (size_t)b * 64 + 16 * (g2 ^ ((b >> 2) & 3));
        *(half8*)((char*)e_img + off) = H;
    }
    esq_g[bin] = s;
}

// 512 threads = 8 waves. Wave wv: row-half h = wv>>2 (32 rows), bin-quarter
// bq = wv&3 (64 bins of each 256-bin chunk). Wave tile 64 bins x 32 rows.
// LDS 52 KB: [0,48K) three 16KB e-stage buffers (buf0 doubles as xh during
// the prologue), [48K,52K) esq (live whole kernel).
__global__ __launch_bounds__(512) void vq_mfma_kernel(const float* __restrict__ x,
                                                      const _Float16* __restrict__ e_img,
                                                      const float* __restrict__ esq_g,
                                                      const float* __restrict__ embed,
                                                      float* __restrict__ out_idx,
                                                      float* __restrict__ out_q,
                                                      int* __restrict__ list,
                                                      int* __restrict__ counter) {
    __shared__ __align__(16) char smem[53248];
    float* esq_s = (float*)(smem + 49152);

    const int t = threadIdx.x;
    const int wv = t >> 6, lane = t & 63, q = lane >> 4, L15 = lane & 15;
    const int h = wv >> 2, bq = wv & 3;
    const int R0 = blockIdx.x * 64;

    // ---- stage esq -> LDS; convert x tile (64 rows) -> fp16 in LDS (buf0) ----
    {
        esq_s[t] = esq_g[t];
        esq_s[t + 512] = esq_g[t + 512];
        const float4* xg = (const float4*)(x + (size_t)R0 * DIM);
#pragma unroll
        for (int qq = 0; qq < 2; ++qq) {
            int G = qq * 512 + t;
            int row = G >> 4, g = G & 15;
            float4 v0 = xg[row * 32 + 2 * g];
            float4 v1 = xg[row * 32 + 2 * g + 1];
            float f[8] = {v0.x, v0.y, v0.z, v0.w, v1.x, v1.y, v1.z, v1.w};
            half8 H;
#pragma unroll
            for (int j = 0; j < 8; ++j) H[j] = (_Float16)f[j];
            int off = row * 256 + 16 * (g ^ (row & 7));
            *(half8*)(smem + off) = H;
        }
    }
    __syncthreads();

    // ---- preload x B-fragments: rows 32h+16nt+L15, k-group (ks<<2)|q ----
    half8 bh[4][2];
    const int rbase = (32 * h + L15) * 256;
#pragma unroll
    for (int ks = 0; ks < 4; ++ks) {
        const int sB = 16 * ((((ks << 2) | q)) ^ (L15 & 7));
#pragma unroll
        for (int nt = 0; nt < 2; ++nt)
            bh[ks][nt] = *(const half8*)(smem + rbase + nt * 4096 + sB);
    }
    __syncthreads();   // xh (buf0 region) dead -> e-stage buffer 0

    const int aOff = (64 * bq + L15) * 64 + 16 * (q ^ ((L15 >> 2) & 3));

    // ---- prologue prefetch: stages 0,1 -> buf0,buf1 (2 KB per wave each) ----
    {
        const char* src = (const char*)e_img;
#pragma unroll
        for (int st = 0; st < 2; ++st)
#pragma unroll
            for (int i = 0; i < 2; ++i) {
                int off = ((i << 3) | wv) << 10;
                glds16(src + ((size_t)st << 14) + off + lane * 16, smem + st * 16384 + off);
            }
        asm volatile("s_waitcnt vmcnt(2)" ::: "memory");   // stage-0 pair landed
    }
    __builtin_amdgcn_s_barrier();
    asm volatile("" ::: "memory");                         // no reads hoist above barrier

    float best[2], sec[2];
    int bidx[2];
#pragma unroll
    for (int nt = 0; nt < 2; ++nt) { best[nt] = -3.4e38f; sec[nt] = -3.4e38f; bidx[nt] = 0; }

    for (int c = 0; c < 4; ++c) {                 // 4 chunks of 256 bins
        f32x4 acc[4][2];
#pragma unroll
        for (int mt = 0; mt < 4; ++mt)
#pragma unroll
            for (int nt = 0; nt < 2; ++nt) acc[mt][nt] = (f32x4){0.f, 0.f, 0.f, 0.f};

#pragma unroll
        for (int s = 0; s < 4; ++s) {             // 4 k-stages of 32
            const int gs = c * 4 + s;
            // issue prefetch of stage gs+2 first: overlaps this stage's MFMAs.
            // dst buf (gs+2)%3 == (gs-1)%3: readers done at entry barrier.
            if (gs < 14) {
                const char* src = (const char*)e_img + ((size_t)(gs + 2) << 14);
                char* dst = smem + ((gs + 2) % 3) * 16384;
#pragma unroll
                for (int i = 0; i < 2; ++i) {
                    int off = ((i << 3) | wv) << 10;
                    glds16(src + off + lane * 16, dst + off);
                }
            }
            const char* buf = smem + (gs % 3) * 16384;
            half8 a[4];
#pragma unroll
            for (int mt = 0; mt < 4; ++mt)
                a[mt] = *(const half8*)(buf + aOff + mt * 1024);
#pragma unroll
            for (int mt = 0; mt < 4; ++mt)
#pragma unroll
                for (int nt = 0; nt < 2; ++nt)
                    acc[mt][nt] = __builtin_amdgcn_mfma_f32_16x16x32_f16(a[mt], bh[s][nt], acc[mt][nt], 0, 0, 0);
            // counted wait: keep newest stage's 2 loads in flight, guarantee
            // stage gs+1's pair (the oldest outstanding) has landed.
            if (gs < 14) {
                asm volatile("s_waitcnt vmcnt(2)" ::: "memory");
            } else if (gs == 14) {
                asm volatile("s_waitcnt vmcnt(0)" ::: "memory");
            }
            __builtin_amdgcn_s_barrier();
            asm volatile("" ::: "memory");        // pin next stage's ds_reads below
        }

        // ---- chunk epilogue: per-lane top-2 over its 16 bins (ascending) ----
#pragma unroll
        for (int mt = 0; mt < 4; ++mt)
#pragma unroll
            for (int r = 0; r < 4; ++r) {
                int bin = 256 * c + 64 * bq + 16 * mt + 4 * q + r;
                float e2 = esq_s[bin];
#pragma unroll
                for (int nt = 0; nt < 2; ++nt) {
                    float sc = 2.f * acc[mt][nt][r] - e2;
                    if (sc > best[nt]) { sec[nt] = best[nt]; best[nt] = sc; bidx[nt] = bin; }
                    else if (sc > sec[nt]) sec[nt] = sc;
                }
            }
    }

    // ---- cross-quad top-2 merge (within wave) ----
#pragma unroll
    for (int nt = 0; nt < 2; ++nt) {
        for (int off = 16; off <= 32; off <<= 1) {
            float ob = __shfl_xor(best[nt], off);
            float os = __shfl_xor(sec[nt], off);
            int oi = __shfl_xor(bidx[nt], off);
            if (ob > best[nt]) { sec[nt] = fmaxf(best[nt], os); best[nt] = ob; bidx[nt] = oi; }
            else sec[nt] = fmaxf(sec[nt], ob);
        }
    }
    __syncthreads();                              // full drain; e-bufs dead -> scratch
    float* sv = (float*)smem;                     // [8 waves][32 rows][b,s,i]
    int* fidx = (int*)(smem + 4096);              // [64]
    if (q == 0) {
#pragma unroll
        for (int nt = 0; nt < 2; ++nt) {
            int base = (wv * 32 + 16 * nt + L15) * 3;
            sv[base] = best[nt]; sv[base + 1] = sec[nt];
            ((int*)sv)[base + 2] = bidx[nt];
        }
    }
    __syncthreads();
    if (t < 64) {
        int hh = t >> 5, r32 = t & 31;
        int base0 = ((4 * hh) * 32 + r32) * 3;
        float b0 = sv[base0], s0 = sv[base0 + 1];
        int i0 = ((int*)sv)[base0 + 2];
        for (int w = 1; w < 4; ++w) {
            int base = ((4 * hh + w) * 32 + r32) * 3;
            float ob = sv[base], os = sv[base + 1];
            int oi = ((int*)sv)[base + 2];
            if (ob > b0) { s0 = fmaxf(b0, os); b0 = ob; i0 = oi; }
            else s0 = fmaxf(s0, ob);
        }
        out_idx[R0 + t] = (float)i0;
        fidx[t] = i0;
        if (b0 - s0 < MARGIN) {
            int pos = atomicAdd(counter, 1);
            list[pos] = R0 + t;
        }
    }
    __syncthreads();

    // ---- fused gather: 64 rows x 32 float4 = 4 per thread ----
    {
        const float4* eg = (const float4*)embed;
        float4* og = (float4*)(out_q + (size_t)R0 * DIM);
#pragma unroll
        for (int i = 0; i < 4; ++i) {
            int f = i * 512 + t;
            int r = f >> 5, cc = f & 31;
            og[(size_t)r * 32 + cc] = eg[(size_t)fidx[r] * 32 + cc];
        }
    }
}

// Compacted exact fp32 refine (16 flagged rows x 1024 bins per tile), with
// fused gather for its rows. First-max tie-break = reference semantics.
#define SWB(r, c4) ((r) * 128 + 4 * ((c4) ^ ((r) & 31)))
__global__ __launch_bounds__(256) void refine_kernel(const float* __restrict__ x,
                                                     const float* __restrict__ embed,
                                                     const float* __restrict__ esq_g,
                                                     float* __restrict__ out_idx,
                                                     float* __restrict__ out_q,
                                                     const int* __restrict__ list,
                                                     const int* __restrict__ counter) {
    __shared__ float xr[16 * 128];    // 8 KB
    __shared__ float bs[64 * 128];    // 32 KB
    __shared__ int rowbuf[16];
    __shared__ int ridx[16];

    const int t = threadIdx.x;
    const int tx = t & 63;
    const int ty = t >> 6;
    const int F = *counter;

    for (int tile = blockIdx.x; tile * 16 < F; tile += gridDim.x) {
        const int base = tile * 16;
        __syncthreads();
        if (t < 16) rowbuf[t] = list[min(base + t, F - 1)];
        __syncthreads();
#pragma unroll
        for (int i = 0; i < 2; ++i) {
            int f = i * 256 + t;
            int r = f >> 5, cc = f & 31;
            float4 v = ((const float4*)(x + (size_t)rowbuf[r] * DIM))[cc];
            *(float4*)&xr[r * 128 + cc * 4] = v;
        }

        float bb[4]; int bi[4];
#pragma unroll
        for (int rr = 0; rr < 4; ++rr) { bb[rr] = -3.4e38f; bi[rr] = 0; }

        for (int chunk = 0; chunk < 16; ++chunk) {
            __syncthreads();
            const float4* eg = (const float4*)(embed + (size_t)chunk * 64 * DIM);
#pragma unroll
            for (int i = 0; i < 8; ++i) {
                int f = i * 256 + t;
                int r = f >> 5, cc = f & 31;
                float4 v = eg[f];
                *(float4*)&bs[SWB(r, cc)] = v;
            }
            __syncthreads();

            float acc[4];
#pragma unroll
            for (int rr = 0; rr < 4; ++rr) acc[rr] = 0.f;
#pragma unroll 8
            for (int k4 = 0; k4 < 32; ++k4) {
                float4 b = *(const float4*)&bs[SWB(tx, k4)];
#pragma unroll
                for (int rr = 0; rr < 4; ++rr) {
                    float4 a = *(const float4*)&xr[(4 * ty + rr) * 128 + k4 * 4];
                    acc[rr] = fmaf(a.x, b.x, acc[rr]);
                    acc[rr] = fmaf(a.y, b.y, acc[rr]);
                    acc[rr] = fmaf(a.z, b.z, acc[rr]);
                    acc[rr] = fmaf(a.w, b.w, acc[rr]);
                }
            }
            const int bin = chunk * 64 + tx;
            const float e2 = esq_g[bin];
#pragma unroll
            for (int rr = 0; rr < 4; ++rr) {
                float sc = 2.f * acc[rr] - e2;
                if (sc > bb[rr]) { bb[rr] = sc; bi[rr] = bin; }
            }
        }

        __syncthreads();
        float* vals = bs;
        int* idxs = (int*)(bs + 1024);
#pragma unroll
        for (int rr = 0; rr < 4; ++rr) {
            vals[(4 * ty + rr) * 64 + tx] = bb[rr];
            idxs[(4 * ty + rr) * 64 + tx] = bi[rr];
        }
        __syncthreads();
        if (t < 16) {
            float bv = vals[t * 64];
            int bix = idxs[t * 64];
            for (int j = 1; j < 64; ++j) {
                float v = vals[t * 64 + j];
                int id = idxs[t * 64 + j];
                if (v > bv || (v == bv && id < bix)) { bv = v; bix = id; }
            }
            ridx[t] = bix;
            if (base + t < F) out_idx[rowbuf[t]] = (float)bix;
        }
        __syncthreads();
        // fused gather for this tile's rows (dup tail rows rewrite same data)
        {
            const float4* eg = (const float4*)embed;
#pragma unroll
            for (int i = 0; i < 2; ++i) {
                int f = i * 256 + t;
                int r = f >> 5, cc = f & 31;
                float4* og = (float4*)(out_q + (size_t)rowbuf[r] * DIM);
                og[cc] = eg[(size_t)ridx[r] * 32 + cc];
            }
        }
    }
}

extern "C" void kernel_launch(void* const* d_in, const int* in_sizes, int n_in,
                              void* d_out, int out_size, void* d_ws, size_t ws_size,
                              hipStream_t stream) {
    const float* x = (const float*)d_in[0];
    const float* embed = (const float*)d_in[1];
    float* out_q = (float*)d_out;
    float* out_idx = out_q + (size_t)N_ROWS * DIM;
    char* wsb = (char*)d_ws;
    _Float16* e_img = (_Float16*)wsb;                         // 256 KB (16 x 16 KB)
    float* esq_g = (float*)(wsb + (16 << 14));                // 4 KB
    int* counter = (int*)(wsb + (16 << 14) + 4096);           // 4 B (+pad)
    int* list = (int*)(wsb + (16 << 14) + 4096 + 128);        // 512 KB

    prep_kernel<<<BINS / 256, 256, 0, stream>>>(embed, e_img, esq_g, counter);
    vq_mfma_kernel<<<N_ROWS / 64, 512, 0, stream>>>(x, e_img, esq_g, embed,
                                                    out_idx, out_q, list, counter);
    refine_kernel<<<1024, 256, 0, stream>>>(x, embed, esq_g, out_idx, out_q, list, counter);
}